// Round 2
// baseline (276.905 us; speedup 1.0000x reference)
//
#include <hip/hip_runtime.h>
#include <hip/hip_bf16.h>

#define BB 8
#define SS 4096
#define DD 1024
#define NN 64
#define ROWS (BB * SS)          // 32768
#define GLD 256                 // 4 gates * 64
#define NCHUNK 128              // chunks per sequence
#define CLEN 32                 // steps per chunk (NCHUNK*CLEN == SS)

using bf16x8 = __attribute__((ext_vector_type(8))) short;
using f32x4  = __attribute__((ext_vector_type(4))) float;
typedef unsigned short ushort_t;

__device__ __forceinline__ ushort_t f2b(float f) {
    union { float f; unsigned int u; } v; v.f = f;
    unsigned int u = v.u;
    return (ushort_t)((u + 0x7fffu + ((u >> 16) & 1u)) >> 16);
}
__device__ __forceinline__ float b2f(ushort_t h) {
    union { unsigned int u; float f; } v; v.u = ((unsigned int)h) << 16;
    return v.f;
}

// ---------------- prep: split gate weights to bf16 hi/lo, Wp to bf16, pack biases ----------------
__global__ void prep_kernel(const float* __restrict__ Wi, const float* __restrict__ bi,
                            const float* __restrict__ Wf, const float* __restrict__ bfv,
                            const float* __restrict__ Wz, const float* __restrict__ bz,
                            const float* __restrict__ Wo, const float* __restrict__ bo,
                            const float* __restrict__ Wp,
                            ushort_t* __restrict__ Wh, ushort_t* __restrict__ Wl,
                            ushort_t* __restrict__ Wpb, float* __restrict__ b_all) {
    int i = blockIdx.x * 256 + threadIdx.x;
    if (i < 256 * 1024) {
        int g = i >> 16;            // 64*1024 = 65536 elems per gate weight
        int rem = i & 65535;
        const float* W = (g == 0) ? Wi : (g == 1) ? Wf : (g == 2) ? Wz : Wo;
        float w = W[rem];
        ushort_t hi = f2b(w);
        Wh[i] = hi;
        Wl[i] = f2b(w - b2f(hi));
    } else if (i < 256 * 1024 + 1024 * 64) {
        int j = i - 256 * 1024;
        Wpb[j] = f2b(Wp[j]);
    } else if (i < 256 * 1024 + 1024 * 64 + 256) {
        int j = i - (256 * 1024 + 1024 * 64);
        const float* bs = (j < 64) ? bi : (j < 128) ? bfv : (j < 192) ? bz : bo;
        b_all[j] = bs[j & 63];
    }
}

// ---------------- LN stats: per-row mean & rstd ----------------
__global__ __launch_bounds__(256) void ln_stats(const float* __restrict__ x,
                                                float2* __restrict__ stats) {
    int row = blockIdx.x * 4 + (threadIdx.x >> 6);
    int lane = threadIdx.x & 63;
    const float4* xr = reinterpret_cast<const float4*>(x + (size_t)row * DD);
    float s1 = 0.0f, s2 = 0.0f;
    #pragma unroll
    for (int j = 0; j < 4; ++j) {
        float4 v = xr[lane + 64 * j];
        s1 += v.x + v.y + v.z + v.w;
        s2 += v.x * v.x + v.y * v.y + v.z * v.z + v.w * v.w;
    }
    #pragma unroll
    for (int off = 1; off < 64; off <<= 1) {
        s1 += __shfl_xor(s1, off);
        s2 += __shfl_xor(s2, off);
    }
    if (lane == 0) {
        float mu = s1 * (1.0f / DD);
        float var = s2 * (1.0f / DD) - mu * mu;
        float2 st; st.x = mu; st.y = rsqrtf(var + 1e-5f);
        stats[row] = st;
    }
}

// ---------------- fused LN + gate GEMM (split-bf16 3-pass for fp32 accuracy) ----------------
// block: 512 thr = 8 waves (2 M x 4 N). Block tile 128 rows x 256 cols. Wave tile 64x64.
__global__ __launch_bounds__(512) void gate_gemm(const float* __restrict__ x,
                                                 const float2* __restrict__ stats,
                                                 const float* __restrict__ ln_w,
                                                 const float* __restrict__ ln_b,
                                                 const ushort_t* __restrict__ Wh,
                                                 const ushort_t* __restrict__ Wl,
                                                 const float* __restrict__ b_all,
                                                 float* __restrict__ gates) {
    int bm = blockIdx.x * 128;
    int tid = threadIdx.x;
    int wid = tid >> 6, lane = tid & 63;
    int wm = wid >> 2, wn = wid & 3;     // wn == gate index
    int r0 = bm + wm * 64;
    int c0 = wn * 64;
    int lrow = lane & 15, lk = (lane >> 4) * 8;

    float rs[4], murs[4];
    #pragma unroll
    for (int mf = 0; mf < 4; ++mf) {
        float2 st = stats[r0 + mf * 16 + lrow];
        rs[mf] = st.y;
        murs[mf] = st.x * st.y;
    }

    f32x4 acc[4][4] = {};
    for (int kk = 0; kk < DD; kk += 32) {
        const float4* wp  = reinterpret_cast<const float4*>(ln_w + kk + lk);
        const float4* bp_ = reinterpret_cast<const float4*>(ln_b + kk + lk);
        float4 w0 = wp[0],  w1 = wp[1];
        float4 b0 = bp_[0], b1 = bp_[1];
        float lw[8] = {w0.x, w0.y, w0.z, w0.w, w1.x, w1.y, w1.z, w1.w};
        float lb[8] = {b0.x, b0.y, b0.z, b0.w, b1.x, b1.y, b1.z, b1.w};

        bf16x8 ah[4], al[4];
        #pragma unroll
        for (int mf = 0; mf < 4; ++mf) {
            const float4* xp = reinterpret_cast<const float4*>(
                x + (size_t)(r0 + mf * 16 + lrow) * DD + kk + lk);
            float4 v0 = xp[0], v1 = xp[1];
            float xv[8] = {v0.x, v0.y, v0.z, v0.w, v1.x, v1.y, v1.z, v1.w};
            #pragma unroll
            for (int e = 0; e < 8; ++e) {
                float xn = (xv[e] * rs[mf] - murs[mf]) * lw[e] + lb[e];
                ushort_t hi = f2b(xn);
                float lo = xn - b2f(hi);
                ah[mf][e] = (short)hi;
                al[mf][e] = (short)f2b(lo);
            }
        }
        bf16x8 bh[4], bl[4];
        #pragma unroll
        for (int nf = 0; nf < 4; ++nf) {
            size_t off = (size_t)(c0 + nf * 16 + lrow) * DD + kk + lk;
            bh[nf] = *reinterpret_cast<const bf16x8*>(Wh + off);
            bl[nf] = *reinterpret_cast<const bf16x8*>(Wl + off);
        }
        #pragma unroll
        for (int mf = 0; mf < 4; ++mf) {
            #pragma unroll
            for (int nf = 0; nf < 4; ++nf) {
                acc[mf][nf] = __builtin_amdgcn_mfma_f32_16x16x32_bf16(ah[mf], bh[nf], acc[mf][nf], 0, 0, 0);
                acc[mf][nf] = __builtin_amdgcn_mfma_f32_16x16x32_bf16(ah[mf], bl[nf], acc[mf][nf], 0, 0, 0);
                acc[mf][nf] = __builtin_amdgcn_mfma_f32_16x16x32_bf16(al[mf], bh[nf], acc[mf][nf], 0, 0, 0);
            }
        }
    }
    int rb = (lane >> 4) * 4;
    #pragma unroll
    for (int mf = 0; mf < 4; ++mf) {
        #pragma unroll
        for (int nf = 0; nf < 4; ++nf) {
            int col = c0 + nf * 16 + (lane & 15);
            float bias = b_all[col];
            #pragma unroll
            for (int r = 0; r < 4; ++r) {
                int row = r0 + mf * 16 + rb + r;
                float v = acc[mf][nf][r] + bias;
                float res;
                if (wn == 0 || wn == 1)      res = fminf(fmaxf(v, -20.0f), 20.0f);
                else if (wn == 2)            res = tanhf(v);
                else                         res = 1.0f / (1.0f + expf(-v));
                gates[(size_t)row * GLD + col] = res;
            }
        }
    }
}

// ---------------- scan phase A: per-chunk summaries ----------------
__global__ __launch_bounds__(256) void scan_a(const float* __restrict__ gates,
                                              float* __restrict__ sLf,
                                              float* __restrict__ sM,
                                              float* __restrict__ sC) {
    int w = blockIdx.x * 4 + (threadIdx.x >> 6);
    int lane = threadIdx.x & 63;
    int b = w >> 7, k = w & (NCHUNK - 1);
    int t0 = k * CLEN;
    const float* gp = gates + ((size_t)(b * SS + t0)) * GLD + lane;
    float Lf = 0.0f, m = -1e30f, c = 0.0f;
    for (int t = 0; t < CLEN; ++t) {
        float li = gp[0], lf = gp[64], z = gp[128];
        gp += GLD;
        Lf += lf;
        float ma = m + lf;
        float mn = fmaxf(ma, li);
        c = expf(ma - mn) * c + expf(li - mn) * z;
        m = mn;
    }
    int idx = (b * NCHUNK + k) * 64 + lane;
    sLf[idx] = Lf; sM[idx] = m; sC[idx] = c;
}

// ---------------- scan phase B: sequential compose over chunks ----------------
__global__ __launch_bounds__(512) void scan_b(const float* __restrict__ sLf,
                                              const float* __restrict__ sM,
                                              const float* __restrict__ sC,
                                              float* __restrict__ cM,
                                              float* __restrict__ cC) {
    int tid = threadIdx.x;
    int b = tid >> 6, lane = tid & 63;
    float c = 0.0f, m = 0.0f;   // reference init: c0=0, m0=0
    for (int k = 0; k < NCHUNK; ++k) {
        int idx = (b * NCHUNK + k) * 64 + lane;
        cM[idx] = m; cC[idx] = c;
        float Lf = sLf[idx], ml = sM[idx], cl = sC[idx];
        float ma = m + Lf;
        float mo = fmaxf(ma, ml);
        c = expf(ma - mo) * c + expf(ml - mo) * cl;
        m = mo;
    }
}

// ---------------- scan phase C: replay chunks, emit h (bf16) ----------------
__global__ __launch_bounds__(256) void scan_c(const float* __restrict__ gates,
                                              const float* __restrict__ cM,
                                              const float* __restrict__ cC,
                                              ushort_t* __restrict__ h) {
    int w = blockIdx.x * 4 + (threadIdx.x >> 6);
    int lane = threadIdx.x & 63;
    int b = w >> 7, k = w & (NCHUNK - 1);
    int t0 = k * CLEN;
    int idx = (b * NCHUNK + k) * 64 + lane;
    float m = cM[idx], c = cC[idx];
    const float* gp = gates + ((size_t)(b * SS + t0)) * GLD + lane;
    ushort_t* hp = h + ((size_t)(b * SS + t0)) * NN + lane;
    for (int t = 0; t < CLEN; ++t) {
        float li = gp[0], lf = gp[64], z = gp[128], o = gp[192];
        gp += GLD;
        float ma = m + lf;
        float mn = fmaxf(ma, li);
        c = expf(ma - mn) * c + expf(li - mn) * z;
        m = mn;
        *hp = f2b(o * tanhf(c));
        hp += NN;
    }
}

// ---------------- output projection: h(32768x64) * Wpb^T(1024x64) + bp -> out ----------------
__global__ __launch_bounds__(256) void out_gemm(const ushort_t* __restrict__ h,
                                                const ushort_t* __restrict__ Wpb,
                                                const float* __restrict__ bp,
                                                float* __restrict__ out) {
    int tid = threadIdx.x, wid = tid >> 6, lane = tid & 63;
    int r0 = (blockIdx.x >> 1) * 32;
    int c0 = (blockIdx.x & 1) * 512 + wid * 128;
    int lrow = lane & 15, lk = (lane >> 4) * 8;

    f32x4 acc[2][8] = {};
    #pragma unroll
    for (int ks = 0; ks < 2; ++ks) {
        int kk = ks * 32;
        bf16x8 a[2], bfr[8];
        #pragma unroll
        for (int mf = 0; mf < 2; ++mf)
            a[mf] = *reinterpret_cast<const bf16x8*>(h + (size_t)(r0 + mf * 16 + lrow) * NN + kk + lk);
        #pragma unroll
        for (int nf = 0; nf < 8; ++nf)
            bfr[nf] = *reinterpret_cast<const bf16x8*>(Wpb + (size_t)(c0 + nf * 16 + lrow) * NN + kk + lk);
        #pragma unroll
        for (int mf = 0; mf < 2; ++mf)
            #pragma unroll
            for (int nf = 0; nf < 8; ++nf)
                acc[mf][nf] = __builtin_amdgcn_mfma_f32_16x16x32_bf16(a[mf], bfr[nf], acc[mf][nf], 0, 0, 0);
    }
    int rb = (lane >> 4) * 4;
    #pragma unroll
    for (int nf = 0; nf < 8; ++nf) {
        int col = c0 + nf * 16 + (lane & 15);
        float bias = bp[col];
        #pragma unroll
        for (int mf = 0; mf < 2; ++mf) {
            #pragma unroll
            for (int r = 0; r < 4; ++r) {
                int row = r0 + mf * 16 + rb + r;
                out[(size_t)row * DD + col] = acc[mf][nf][r] + bias;
            }
        }
    }
}

extern "C" void kernel_launch(void* const* d_in, const int* in_sizes, int n_in,
                              void* d_out, int out_size, void* d_ws, size_t ws_size,
                              hipStream_t stream) {
    const float* x    = (const float*)d_in[0];
    const float* ln_w = (const float*)d_in[1];
    const float* ln_b = (const float*)d_in[2];
    const float* Wi   = (const float*)d_in[3];
    const float* bi   = (const float*)d_in[4];
    const float* Wf   = (const float*)d_in[5];
    const float* bfv  = (const float*)d_in[6];
    const float* Wz   = (const float*)d_in[7];
    const float* bz   = (const float*)d_in[8];
    const float* Wo   = (const float*)d_in[9];
    const float* bo   = (const float*)d_in[10];
    const float* Wp   = (const float*)d_in[11];
    const float* bp   = (const float*)d_in[12];
    float* out = (float*)d_out;

    // gates fp32 [32768][256] live at d_out offset 0 (33.5 MB; dead before out_gemm writes)
    float* gates = (float*)d_out;

    // Small scratch in ws (~7 MB)
    char* w = (char*)d_ws;
    ushort_t* h   = (ushort_t*)w; w += (size_t)ROWS * NN * 2;       // 4,194,304
    ushort_t* Wh  = (ushort_t*)w; w += 256 * 1024 * 2;              // 524,288
    ushort_t* Wl  = (ushort_t*)w; w += 256 * 1024 * 2;              // 524,288
    ushort_t* Wpb = (ushort_t*)w; w += 1024 * 64 * 2;               // 131,072
    float* b_all  = (float*)w;    w += 256 * 4;                     // 1,024
    float2* stats = (float2*)w;   w += ROWS * 8;                    // 262,144
    float* sLf    = (float*)w;    w += BB * NCHUNK * 64 * 4;        // 262,144
    float* sM     = (float*)w;    w += BB * NCHUNK * 64 * 4;
    float* sC     = (float*)w;    w += BB * NCHUNK * 64 * 4;
    float* cM     = (float*)w;    w += BB * NCHUNK * 64 * 4;
    float* cC     = (float*)w;    w += BB * NCHUNK * 64 * 4;

    prep_kernel<<<1282, 256, 0, stream>>>(Wi, bi, Wf, bfv, Wz, bz, Wo, bo, Wp, Wh, Wl, Wpb, b_all);
    ln_stats<<<ROWS / 4, 256, 0, stream>>>(x, stats);
    gate_gemm<<<ROWS / 128, 512, 0, stream>>>(x, stats, ln_w, ln_b, Wh, Wl, b_all, gates);
    scan_a<<<(BB * NCHUNK) / 4, 256, 0, stream>>>(gates, sLf, sM, sC);
    scan_b<<<1, 512, 0, stream>>>(sLf, sM, sC, cM, cC);
    scan_c<<<(BB * NCHUNK) / 4, 256, 0, stream>>>(gates, cM, cC, h);
    out_gemm<<<(ROWS / 32) * 2, 256, 0, stream>>>(h, Wpb, bp, out);
}

// Round 3
// 237.876 us; speedup vs baseline: 1.1641x; 1.1641x over previous
//
#include <hip/hip_runtime.h>
#include <hip/hip_bf16.h>

#define BB 8
#define SS 4096
#define DD 1024
#define NN 64
#define ROWS (BB * SS)          // 32768
#define GLD 256                 // 4 gates * 64
#define NCHUNK 256              // chunks per sequence
#define CLEN 16                 // steps per chunk (NCHUNK*CLEN == SS)

using bf16x8 = __attribute__((ext_vector_type(8))) short;
using f32x4  = __attribute__((ext_vector_type(4))) float;
typedef unsigned short ushort_t;

__device__ __forceinline__ ushort_t f2b(float f) {
    union { float f; unsigned int u; } v; v.f = f;
    unsigned int u = v.u;
    return (ushort_t)((u + 0x7fffu + ((u >> 16) & 1u)) >> 16);
}
__device__ __forceinline__ float b2f(ushort_t h) {
    union { unsigned int u; float f; } v; v.u = ((unsigned int)h) << 16;
    return v.f;
}

// ---------------- prep: split gate weights to bf16 hi/lo, Wp to bf16, pack biases ----------------
__global__ void prep_kernel(const float* __restrict__ Wi, const float* __restrict__ bi,
                            const float* __restrict__ Wf, const float* __restrict__ bfv,
                            const float* __restrict__ Wz, const float* __restrict__ bz,
                            const float* __restrict__ Wo, const float* __restrict__ bo,
                            const float* __restrict__ Wp,
                            ushort_t* __restrict__ Wh, ushort_t* __restrict__ Wl,
                            ushort_t* __restrict__ Wpb, float* __restrict__ b_all) {
    int i = blockIdx.x * 256 + threadIdx.x;
    if (i < 256 * 1024) {
        int g = i >> 16;
        int rem = i & 65535;
        const float* W = (g == 0) ? Wi : (g == 1) ? Wf : (g == 2) ? Wz : Wo;
        float w = W[rem];
        ushort_t hi = f2b(w);
        Wh[i] = hi;
        Wl[i] = f2b(w - b2f(hi));
    } else if (i < 256 * 1024 + 1024 * 64) {
        int j = i - 256 * 1024;
        Wpb[j] = f2b(Wp[j]);
    } else if (i < 256 * 1024 + 1024 * 64 + 256) {
        int j = i - (256 * 1024 + 1024 * 64);
        const float* bs = (j < 64) ? bi : (j < 128) ? bfv : (j < 192) ? bz : bo;
        b_all[j] = bs[j & 63];
    }
}

// ---------------- LN stats: per-row mean & rstd ----------------
__global__ __launch_bounds__(256) void ln_stats(const float* __restrict__ x,
                                                float2* __restrict__ stats) {
    int row = blockIdx.x * 4 + (threadIdx.x >> 6);
    int lane = threadIdx.x & 63;
    const float4* xr = reinterpret_cast<const float4*>(x + (size_t)row * DD);
    float s1 = 0.0f, s2 = 0.0f;
    #pragma unroll
    for (int j = 0; j < 4; ++j) {
        float4 v = xr[lane + 64 * j];
        s1 += v.x + v.y + v.z + v.w;
        s2 += v.x * v.x + v.y * v.y + v.z * v.z + v.w * v.w;
    }
    #pragma unroll
    for (int off = 1; off < 64; off <<= 1) {
        s1 += __shfl_xor(s1, off);
        s2 += __shfl_xor(s2, off);
    }
    if (lane == 0) {
        float mu = s1 * (1.0f / DD);
        float var = s2 * (1.0f / DD) - mu * mu;
        float2 st; st.x = mu; st.y = rsqrtf(var + 1e-5f);
        stats[row] = st;
    }
}

// ---------------- fused LN + gate GEMM, LDS-staged, 2-phase double-buffered ----------------
// block: 512 thr = 8 waves (2M x 4N). Tile 128 rows x 256 cols. Wave 64x64. Grid 256.
__global__ __launch_bounds__(512) void gate_gemm(const float* __restrict__ x,
                                                 const float2* __restrict__ stats,
                                                 const float* __restrict__ ln_w,
                                                 const float* __restrict__ ln_b,
                                                 const ushort_t* __restrict__ Wh,
                                                 const ushort_t* __restrict__ Wl,
                                                 const float* __restrict__ b_all,
                                                 float* __restrict__ gates) {
    int bm = blockIdx.x * 128;
    int tid = threadIdx.x;
    int wid = tid >> 6, lane = tid & 63;
    int wm = wid >> 2, wn = wid & 3;     // wn == gate index
    int c0 = wn * 64;
    int lrow = lane & 15, lkg = lane >> 4;

    // staging role: thread -> (srow, skg)
    int srow = tid & 127;
    int skg  = tid >> 7;                 // wave-uniform
    const float4* xld = reinterpret_cast<const float4*>(x + (size_t)(bm + srow) * DD) + skg * 2;
    float2 st = stats[bm + srow];
    float s_rs = st.y, s_murs = st.x * st.y;

    // LDS: [buf][kgroup][row][8] bf16, hi and lo planes (16 KB each)
    __shared__ ushort_t lds_h[2][4][128][8];
    __shared__ ushort_t lds_l[2][4][128][8];

    // prologue: stage step 0 into buf 0
    {
        float4 v0 = xld[0], v1 = xld[1];
        const float4* wp  = reinterpret_cast<const float4*>(ln_w + skg * 8);
        const float4* bp_ = reinterpret_cast<const float4*>(ln_b + skg * 8);
        float4 w0 = wp[0], w1 = wp[1], b0 = bp_[0], b1 = bp_[1];
        float xv[8] = {v0.x, v0.y, v0.z, v0.w, v1.x, v1.y, v1.z, v1.w};
        float lw[8] = {w0.x, w0.y, w0.z, w0.w, w1.x, w1.y, w1.z, w1.w};
        float lb[8] = {b0.x, b0.y, b0.z, b0.w, b1.x, b1.y, b1.z, b1.w};
        bf16x8 hi8, lo8;
        #pragma unroll
        for (int e = 0; e < 8; ++e) {
            float xn = (xv[e] * s_rs - s_murs) * lw[e] + lb[e];
            ushort_t hb = f2b(xn);
            hi8[e] = (short)hb;
            lo8[e] = (short)f2b(xn - b2f(hb));
        }
        *reinterpret_cast<bf16x8*>(&lds_h[0][skg][srow][0]) = hi8;
        *reinterpret_cast<bf16x8*>(&lds_l[0][skg][srow][0]) = lo8;
    }

    f32x4 acc[4][4] = {};
    for (int step = 0; step < 32; ++step) {
        __syncthreads();
        int buf = step & 1;
        if (step < 31) {
            int kk = (step + 1) * 32;
            float4 v0 = xld[(kk >> 2)], v1 = xld[(kk >> 2) + 1];
            const float4* wp  = reinterpret_cast<const float4*>(ln_w + kk + skg * 8);
            const float4* bp_ = reinterpret_cast<const float4*>(ln_b + kk + skg * 8);
            float4 w0 = wp[0], w1 = wp[1], b0 = bp_[0], b1 = bp_[1];
            float xv[8] = {v0.x, v0.y, v0.z, v0.w, v1.x, v1.y, v1.z, v1.w};
            float lw[8] = {w0.x, w0.y, w0.z, w0.w, w1.x, w1.y, w1.z, w1.w};
            float lb[8] = {b0.x, b0.y, b0.z, b0.w, b1.x, b1.y, b1.z, b1.w};
            bf16x8 hi8, lo8;
            #pragma unroll
            for (int e = 0; e < 8; ++e) {
                float xn = (xv[e] * s_rs - s_murs) * lw[e] + lb[e];
                ushort_t hb = f2b(xn);
                hi8[e] = (short)hb;
                lo8[e] = (short)f2b(xn - b2f(hb));
            }
            *reinterpret_cast<bf16x8*>(&lds_h[buf ^ 1][skg][srow][0]) = hi8;
            *reinterpret_cast<bf16x8*>(&lds_l[buf ^ 1][skg][srow][0]) = lo8;
        }
        // compute current step from lds[buf]
        bf16x8 ah[4], al[4];
        #pragma unroll
        for (int mf = 0; mf < 4; ++mf) {
            int row = wm * 64 + mf * 16 + lrow;
            ah[mf] = *reinterpret_cast<const bf16x8*>(&lds_h[buf][lkg][row][0]);
            al[mf] = *reinterpret_cast<const bf16x8*>(&lds_l[buf][lkg][row][0]);
        }
        int kk = step * 32;
        #pragma unroll
        for (int nf = 0; nf < 4; ++nf) {
            size_t off = (size_t)(c0 + nf * 16 + lrow) * DD + kk + lkg * 8;
            bf16x8 bh = *reinterpret_cast<const bf16x8*>(Wh + off);
            bf16x8 bl = *reinterpret_cast<const bf16x8*>(Wl + off);
            #pragma unroll
            for (int mf = 0; mf < 4; ++mf) {
                acc[mf][nf] = __builtin_amdgcn_mfma_f32_16x16x32_bf16(ah[mf], bh, acc[mf][nf], 0, 0, 0);
                acc[mf][nf] = __builtin_amdgcn_mfma_f32_16x16x32_bf16(ah[mf], bl, acc[mf][nf], 0, 0, 0);
                acc[mf][nf] = __builtin_amdgcn_mfma_f32_16x16x32_bf16(al[mf], bh, acc[mf][nf], 0, 0, 0);
            }
        }
    }

    int r0 = bm + wm * 64;
    int rb = (lane >> 4) * 4;
    #pragma unroll
    for (int mf = 0; mf < 4; ++mf) {
        #pragma unroll
        for (int nf = 0; nf < 4; ++nf) {
            int col = c0 + nf * 16 + (lane & 15);
            float bias = b_all[col];
            #pragma unroll
            for (int r = 0; r < 4; ++r) {
                int row = r0 + mf * 16 + rb + r;
                float v = acc[mf][nf][r] + bias;
                float res;
                if (wn == 0 || wn == 1)      res = fminf(fmaxf(v, -20.0f), 20.0f);
                else if (wn == 2)            res = tanhf(v);
                else                         res = 1.0f / (1.0f + expf(-v));
                gates[(size_t)row * GLD + col] = res;
            }
        }
    }
}

// ---------------- scan phase A: per-chunk summaries ----------------
__global__ __launch_bounds__(256) void scan_a(const float* __restrict__ gates,
                                              float* __restrict__ sLf,
                                              float* __restrict__ sM,
                                              float* __restrict__ sC) {
    int w = blockIdx.x * 4 + (threadIdx.x >> 6);
    int lane = threadIdx.x & 63;
    int b = w >> 8, k = w & (NCHUNK - 1);
    int t0 = k * CLEN;
    const float* gp = gates + ((size_t)(b * SS + t0)) * GLD + lane;
    float Lf = 0.0f, m = -1e30f, c = 0.0f;
    for (int t = 0; t < CLEN; ++t) {
        float li = gp[0], lf = gp[64], z = gp[128];
        gp += GLD;
        Lf += lf;
        float ma = m + lf;
        float mn = fmaxf(ma, li);
        c = expf(ma - mn) * c + expf(li - mn) * z;
        m = mn;
    }
    int idx = (b * NCHUNK + k) * 64 + lane;
    sLf[idx] = Lf; sM[idx] = m; sC[idx] = c;
}

// ---------------- scan phase B: sequential compose over chunks (one block per batch) ----------------
__global__ __launch_bounds__(64) void scan_b(const float* __restrict__ sLf,
                                             const float* __restrict__ sM,
                                             const float* __restrict__ sC,
                                             float* __restrict__ cM,
                                             float* __restrict__ cC) {
    int b = blockIdx.x;
    int lane = threadIdx.x;
    float c = 0.0f, m = 0.0f;   // reference init: c0=0, m0=0
    for (int k = 0; k < NCHUNK; ++k) {
        int idx = (b * NCHUNK + k) * 64 + lane;
        cM[idx] = m; cC[idx] = c;
        float Lf = sLf[idx], ml = sM[idx], cl = sC[idx];
        float ma = m + Lf;
        float mo = fmaxf(ma, ml);
        c = expf(ma - mo) * c + expf(ml - mo) * cl;
        m = mo;
    }
}

// ---------------- scan phase C: replay chunks, emit h (bf16) ----------------
__global__ __launch_bounds__(256) void scan_c(const float* __restrict__ gates,
                                              const float* __restrict__ cM,
                                              const float* __restrict__ cC,
                                              ushort_t* __restrict__ h) {
    int w = blockIdx.x * 4 + (threadIdx.x >> 6);
    int lane = threadIdx.x & 63;
    int b = w >> 8, k = w & (NCHUNK - 1);
    int t0 = k * CLEN;
    int idx = (b * NCHUNK + k) * 64 + lane;
    float m = cM[idx], c = cC[idx];
    const float* gp = gates + ((size_t)(b * SS + t0)) * GLD + lane;
    ushort_t* hp = h + ((size_t)(b * SS + t0)) * NN + lane;
    for (int t = 0; t < CLEN; ++t) {
        float li = gp[0], lf = gp[64], z = gp[128], o = gp[192];
        gp += GLD;
        float ma = m + lf;
        float mn = fmaxf(ma, li);
        c = expf(ma - mn) * c + expf(li - mn) * z;
        m = mn;
        *hp = f2b(o * tanhf(c));
        hp += NN;
    }
}

// ---------------- output projection: h(32768x64) * Wpb^T(1024x64) + bp -> out ----------------
__global__ __launch_bounds__(256) void out_gemm(const ushort_t* __restrict__ h,
                                                const ushort_t* __restrict__ Wpb,
                                                const float* __restrict__ bp,
                                                float* __restrict__ out) {
    int tid = threadIdx.x, wid = tid >> 6, lane = tid & 63;
    int r0 = (blockIdx.x >> 1) * 32;
    int c0 = (blockIdx.x & 1) * 512 + wid * 128;
    int lrow = lane & 15, lk = (lane >> 4) * 8;

    f32x4 acc[2][8] = {};
    #pragma unroll
    for (int ks = 0; ks < 2; ++ks) {
        int kk = ks * 32;
        bf16x8 a[2], bfr[8];
        #pragma unroll
        for (int mf = 0; mf < 2; ++mf)
            a[mf] = *reinterpret_cast<const bf16x8*>(h + (size_t)(r0 + mf * 16 + lrow) * NN + kk + lk);
        #pragma unroll
        for (int nf = 0; nf < 8; ++nf)
            bfr[nf] = *reinterpret_cast<const bf16x8*>(Wpb + (size_t)(c0 + nf * 16 + lrow) * NN + kk + lk);
        #pragma unroll
        for (int mf = 0; mf < 2; ++mf)
            #pragma unroll
            for (int nf = 0; nf < 8; ++nf)
                acc[mf][nf] = __builtin_amdgcn_mfma_f32_16x16x32_bf16(a[mf], bfr[nf], acc[mf][nf], 0, 0, 0);
    }
    int rb = (lane >> 4) * 4;
    #pragma unroll
    for (int nf = 0; nf < 8; ++nf) {
        int col = c0 + nf * 16 + (lane & 15);
        float bias = bp[col];
        #pragma unroll
        for (int mf = 0; mf < 2; ++mf) {
            #pragma unroll
            for (int r = 0; r < 4; ++r) {
                int row = r0 + mf * 16 + rb + r;
                out[(size_t)row * DD + col] = acc[mf][nf][r] + bias;
            }
        }
    }
}

extern "C" void kernel_launch(void* const* d_in, const int* in_sizes, int n_in,
                              void* d_out, int out_size, void* d_ws, size_t ws_size,
                              hipStream_t stream) {
    const float* x    = (const float*)d_in[0];
    const float* ln_w = (const float*)d_in[1];
    const float* ln_b = (const float*)d_in[2];
    const float* Wi   = (const float*)d_in[3];
    const float* bi   = (const float*)d_in[4];
    const float* Wf   = (const float*)d_in[5];
    const float* bfv  = (const float*)d_in[6];
    const float* Wz   = (const float*)d_in[7];
    const float* bz   = (const float*)d_in[8];
    const float* Wo   = (const float*)d_in[9];
    const float* bo   = (const float*)d_in[10];
    const float* Wp   = (const float*)d_in[11];
    const float* bp   = (const float*)d_in[12];
    float* out = (float*)d_out;

    // gates fp32 [32768][256] at d_out floats [0, 8.39M)  (33.5 MB; dead before out_gemm)
    float* gates = (float*)d_out;
    // chunk summaries in dead d_out space (floats from 9M; 5 x 131072 floats)
    float* sbase = (float*)d_out + 9 * 1024 * 1024;
    float* sLf = sbase;
    float* sM  = sbase + 1 * (BB * NCHUNK * 64);
    float* sC  = sbase + 2 * (BB * NCHUNK * 64);
    float* cM  = sbase + 3 * (BB * NCHUNK * 64);
    float* cC  = sbase + 4 * (BB * NCHUNK * 64);

    // Small scratch in ws (~5.7 MB)
    char* w = (char*)d_ws;
    ushort_t* h   = (ushort_t*)w; w += (size_t)ROWS * NN * 2;       // 4,194,304
    ushort_t* Wh  = (ushort_t*)w; w += 256 * 1024 * 2;              // 524,288
    ushort_t* Wl  = (ushort_t*)w; w += 256 * 1024 * 2;              // 524,288
    ushort_t* Wpb = (ushort_t*)w; w += 1024 * 64 * 2;               // 131,072
    float* b_all  = (float*)w;    w += 256 * 4;                     // 1,024
    float2* stats = (float2*)w;   w += ROWS * 8;                    // 262,144

    prep_kernel<<<1282, 256, 0, stream>>>(Wi, bi, Wf, bfv, Wz, bz, Wo, bo, Wp, Wh, Wl, Wpb, b_all);
    ln_stats<<<ROWS / 4, 256, 0, stream>>>(x, stats);
    gate_gemm<<<ROWS / 128, 512, 0, stream>>>(x, stats, ln_w, ln_b, Wh, Wl, b_all, gates);
    scan_a<<<(BB * NCHUNK) / 4, 256, 0, stream>>>(gates, sLf, sM, sC);
    scan_b<<<BB, 64, 0, stream>>>(sLf, sM, sC, cM, cC);
    scan_c<<<(BB * NCHUNK) / 4, 256, 0, stream>>>(gates, cM, cC, h);
    out_gemm<<<(ROWS / 32) * 2, 256, 0, stream>>>(h, Wpb, bp, out);
}

// Round 4
// 181.772 us; speedup vs baseline: 1.5234x; 1.3086x over previous
//
#include <hip/hip_runtime.h>
#include <hip/hip_bf16.h>

#define BB 8
#define SS 4096
#define DD 1024
#define NN 64
#define ROWS (BB * SS)          // 32768
#define GLD 256                 // 4 gates * 64
#define NCHUNK 256              // chunks per sequence
#define CLEN 16                 // steps per chunk (NCHUNK*CLEN == SS)

using bf16x8 = __attribute__((ext_vector_type(8))) short;
using f32x4  = __attribute__((ext_vector_type(4))) float;
typedef unsigned short ushort_t;

__device__ __forceinline__ ushort_t f2b(float f) {
    union { float f; unsigned int u; } v; v.f = f;
    unsigned int u = v.u;
    return (ushort_t)((u + 0x7fffu + ((u >> 16) & 1u)) >> 16);
}
__device__ __forceinline__ float b2f(ushort_t h) {
    union { unsigned int u; float f; } v; v.u = ((unsigned int)h) << 16;
    return v.f;
}

// ---------------- prep: W -> fragment-linear packed bf16 hi/lo; Wp -> bf16; biases ----------------
// packed layout: pW[s][cb][lane][8] : element = W[cb*16 + (lane&15)][s*32 + (lane>>4)*8 + e]
__global__ void prep_kernel(const float* __restrict__ Wi, const float* __restrict__ bi,
                            const float* __restrict__ Wf, const float* __restrict__ bfv,
                            const float* __restrict__ Wz, const float* __restrict__ bz,
                            const float* __restrict__ Wo, const float* __restrict__ bo,
                            const float* __restrict__ Wp,
                            ushort_t* __restrict__ Wph, ushort_t* __restrict__ Wpl,
                            ushort_t* __restrict__ Wpb, float* __restrict__ b_all) {
    int i = blockIdx.x * 256 + threadIdx.x;
    if (i < 32768) {
        int l = i & 63, cb = (i >> 6) & 15, s = i >> 10;
        int r = cb * 16 + (l & 15);
        int c = s * 32 + (l >> 4) * 8;
        int g = r >> 6, rem = r & 63;
        const float* W = (g == 0) ? Wi : (g == 1) ? Wf : (g == 2) ? Wz : Wo;
        const float* src = W + rem * 1024 + c;
        bf16x8 hi8, lo8;
        #pragma unroll
        for (int e = 0; e < 8; ++e) {
            float w = src[e];
            ushort_t hb = f2b(w);
            hi8[e] = (short)hb;
            lo8[e] = (short)f2b(w - b2f(hb));
        }
        *reinterpret_cast<bf16x8*>(Wph + (size_t)i * 8) = hi8;
        *reinterpret_cast<bf16x8*>(Wpl + (size_t)i * 8) = lo8;
    } else if (i < 32768 + 65536) {
        int j = i - 32768;
        Wpb[j] = f2b(Wp[j]);
    } else if (i < 32768 + 65536 + 256) {
        int j = i - (32768 + 65536);
        const float* bs = (j < 64) ? bi : (j < 128) ? bfv : (j < 192) ? bz : bo;
        b_all[j] = bs[j & 63];
    }
}

// ---------------- fused LN-stats + LN + gate GEMM ----------------
// block: 512 thr = 8 waves (2M x 4N). Tile 128 rows x 256 cols. Wave 64x64. Grid 256 (1/CU).
__global__ __launch_bounds__(512, 1) void gate_gemm(const float* __restrict__ x,
                                                    const float* __restrict__ ln_w,
                                                    const float* __restrict__ ln_b,
                                                    const ushort_t* __restrict__ Wph,
                                                    const ushort_t* __restrict__ Wpl,
                                                    const float* __restrict__ b_all,
                                                    float* __restrict__ gates) {
    int bm = blockIdx.x * 128;
    int tid = threadIdx.x;
    int wid = tid >> 6, lane = tid & 63;
    int wm = wid >> 2, wn = wid & 3;     // wn == gate index
    int lrow = lane & 15, lkg = lane >> 4;
    int srow = tid >> 2, skg = tid & 3;  // staging: row, 8-col k-group

    const float4* xrow = reinterpret_cast<const float4*>(x + (size_t)(bm + srow) * DD);

    // ---- stats prologue (backward so low cols stay L2-warm) ----
    float s1 = 0.0f, s2 = 0.0f;
    for (int j = 31; j >= 0; --j) {
        float4 v0 = xrow[j * 8 + skg * 2];
        float4 v1 = xrow[j * 8 + skg * 2 + 1];
        s1 += v0.x + v0.y + v0.z + v0.w + v1.x + v1.y + v1.z + v1.w;
        s2 += v0.x * v0.x + v0.y * v0.y + v0.z * v0.z + v0.w * v0.w
            + v1.x * v1.x + v1.y * v1.y + v1.z * v1.z + v1.w * v1.w;
    }
    s1 += __shfl_xor(s1, 1); s2 += __shfl_xor(s2, 1);
    s1 += __shfl_xor(s1, 2); s2 += __shfl_xor(s2, 2);
    float mu = s1 * (1.0f / DD);
    float var = s2 * (1.0f / DD) - mu * mu;
    float s_rs = rsqrtf(var + 1e-5f);
    float s_murs = mu * s_rs;

    // LDS: swizzled bf16 planes, [buf][row*32 + kg*8] ^ ((row&7)<<3); 8KB per buf per plane
    __shared__ ushort_t lds_h[2][4096];
    __shared__ ushort_t lds_l[2][4096];

    auto stageX = [&](int s, int buf) {
        float4 v0 = xrow[s * 8 + skg * 2];
        float4 v1 = xrow[s * 8 + skg * 2 + 1];
        const float4* wp  = reinterpret_cast<const float4*>(ln_w + s * 32 + skg * 8);
        const float4* bp_ = reinterpret_cast<const float4*>(ln_b + s * 32 + skg * 8);
        float4 w0 = wp[0], w1 = wp[1], b0 = bp_[0], b1 = bp_[1];
        float xv[8] = {v0.x, v0.y, v0.z, v0.w, v1.x, v1.y, v1.z, v1.w};
        float lw[8] = {w0.x, w0.y, w0.z, w0.w, w1.x, w1.y, w1.z, w1.w};
        float lb[8] = {b0.x, b0.y, b0.z, b0.w, b1.x, b1.y, b1.z, b1.w};
        bf16x8 hi8, lo8;
        #pragma unroll
        for (int e = 0; e < 8; ++e) {
            float xn = (xv[e] * s_rs - s_murs) * lw[e] + lb[e];
            ushort_t hb = f2b(xn);
            hi8[e] = (short)hb;
            lo8[e] = (short)f2b(xn - b2f(hb));
        }
        int idx = (srow * 32 + skg * 8) ^ ((srow & 7) << 3);
        *reinterpret_cast<bf16x8*>(&lds_h[buf][idx]) = hi8;
        *reinterpret_cast<bf16x8*>(&lds_l[buf][idx]) = lo8;
    };
    auto loadW = [&](bf16x8 (&w)[4][2], int s) {
        #pragma unroll
        for (int nf = 0; nf < 4; ++nf) {
            size_t base = (((size_t)(s * 16 + wn * 4 + nf)) * 64 + lane) * 8;
            w[nf][0] = *reinterpret_cast<const bf16x8*>(Wph + base);
            w[nf][1] = *reinterpret_cast<const bf16x8*>(Wpl + base);
        }
    };
    f32x4 acc[4][4] = {};
    auto compute = [&](int buf, bf16x8 (&w)[4][2]) {
        bf16x8 ah[4], al[4];
        #pragma unroll
        for (int mf = 0; mf < 4; ++mf) {
            int row = wm * 64 + mf * 16 + lrow;
            int idx = (row * 32 + lkg * 8) ^ ((row & 7) << 3);
            ah[mf] = *reinterpret_cast<const bf16x8*>(&lds_h[buf][idx]);
            al[mf] = *reinterpret_cast<const bf16x8*>(&lds_l[buf][idx]);
        }
        #pragma unroll
        for (int nf = 0; nf < 4; ++nf) {
            #pragma unroll
            for (int mf = 0; mf < 4; ++mf) {
                acc[mf][nf] = __builtin_amdgcn_mfma_f32_16x16x32_bf16(ah[mf], w[nf][0], acc[mf][nf], 0, 0, 0);
                acc[mf][nf] = __builtin_amdgcn_mfma_f32_16x16x32_bf16(ah[mf], w[nf][1], acc[mf][nf], 0, 0, 0);
                acc[mf][nf] = __builtin_amdgcn_mfma_f32_16x16x32_bf16(al[mf], w[nf][0], acc[mf][nf], 0, 0, 0);
            }
        }
    };

    bf16x8 wA[4][2], wB[4][2];
    loadW(wA, 0);
    stageX(0, 0);
    for (int it = 0; it < 16; ++it) {
        int s0 = it * 2;
        __syncthreads();
        loadW(wB, s0 + 1);
        stageX(s0 + 1, 1);
        compute(0, wA);
        __syncthreads();
        if (s0 + 2 < 32) {
            loadW(wA, s0 + 2);
            stageX(s0 + 2, 0);
        }
        compute(1, wB);
    }

    int c0 = wn * 64;
    int r0 = bm + wm * 64;
    int rb = (lane >> 4) * 4;
    #pragma unroll
    for (int mf = 0; mf < 4; ++mf) {
        #pragma unroll
        for (int nf = 0; nf < 4; ++nf) {
            int col = c0 + nf * 16 + (lane & 15);
            float bias = b_all[col];
            #pragma unroll
            for (int r = 0; r < 4; ++r) {
                int row = r0 + mf * 16 + rb + r;
                float v = acc[mf][nf][r] + bias;
                float res;
                if (wn == 0 || wn == 1)      res = fminf(fmaxf(v, -20.0f), 20.0f);
                else if (wn == 2)            res = tanhf(v);
                else                         res = 1.0f / (1.0f + expf(-v));
                gates[(size_t)row * GLD + col] = res;
            }
        }
    }
}

// ---------------- scan phase A: per-chunk summaries ----------------
__global__ __launch_bounds__(256) void scan_a(const float* __restrict__ gates,
                                              float* __restrict__ sLf,
                                              float* __restrict__ sM,
                                              float* __restrict__ sC) {
    int w = blockIdx.x * 4 + (threadIdx.x >> 6);
    int lane = threadIdx.x & 63;
    int b = w >> 8, k = w & (NCHUNK - 1);
    int t0 = k * CLEN;
    const float* gp = gates + ((size_t)(b * SS + t0)) * GLD + lane;
    float Lf = 0.0f, m = -1e30f, c = 0.0f;
    for (int t = 0; t < CLEN; ++t) {
        float li = gp[0], lf = gp[64], z = gp[128];
        gp += GLD;
        Lf += lf;
        float ma = m + lf;
        float mn = fmaxf(ma, li);
        c = expf(ma - mn) * c + expf(li - mn) * z;
        m = mn;
    }
    int idx = (b * NCHUNK + k) * 64 + lane;
    sLf[idx] = Lf; sM[idx] = m; sC[idx] = c;
}

// ---------------- scan phase B: sequential compose over chunks (one block per batch) ----------------
__global__ __launch_bounds__(64) void scan_b(const float* __restrict__ sLf,
                                             const float* __restrict__ sM,
                                             const float* __restrict__ sC,
                                             float* __restrict__ cM,
                                             float* __restrict__ cC) {
    int b = blockIdx.x;
    int lane = threadIdx.x;
    float c = 0.0f, m = 0.0f;   // reference init: c0=0, m0=0
    for (int k = 0; k < NCHUNK; ++k) {
        int idx = (b * NCHUNK + k) * 64 + lane;
        cM[idx] = m; cC[idx] = c;
        float Lf = sLf[idx], ml = sM[idx], cl = sC[idx];
        float ma = m + Lf;
        float mo = fmaxf(ma, ml);
        c = expf(ma - mo) * c + expf(ml - mo) * cl;
        m = mo;
    }
}

// ---------------- scan phase C: replay chunks, emit h (bf16) ----------------
__global__ __launch_bounds__(256) void scan_c(const float* __restrict__ gates,
                                              const float* __restrict__ cM,
                                              const float* __restrict__ cC,
                                              ushort_t* __restrict__ h) {
    int w = blockIdx.x * 4 + (threadIdx.x >> 6);
    int lane = threadIdx.x & 63;
    int b = w >> 8, k = w & (NCHUNK - 1);
    int t0 = k * CLEN;
    int idx = (b * NCHUNK + k) * 64 + lane;
    float m = cM[idx], c = cC[idx];
    const float* gp = gates + ((size_t)(b * SS + t0)) * GLD + lane;
    ushort_t* hp = h + ((size_t)(b * SS + t0)) * NN + lane;
    for (int t = 0; t < CLEN; ++t) {
        float li = gp[0], lf = gp[64], z = gp[128], o = gp[192];
        gp += GLD;
        float ma = m + lf;
        float mn = fmaxf(ma, li);
        c = expf(ma - mn) * c + expf(li - mn) * z;
        m = mn;
        *hp = f2b(o * tanhf(c));
        hp += NN;
    }
}

// ---------------- output projection: h(32768x64) * Wpb^T(1024x64) + bp -> out ----------------
__global__ __launch_bounds__(256) void out_gemm(const ushort_t* __restrict__ h,
                                                const ushort_t* __restrict__ Wpb,
                                                const float* __restrict__ bp,
                                                float* __restrict__ out) {
    int tid = threadIdx.x, wid = tid >> 6, lane = tid & 63;
    int r0 = (blockIdx.x >> 1) * 32;
    int c0 = (blockIdx.x & 1) * 512 + wid * 128;
    int lrow = lane & 15, lk = (lane >> 4) * 8;

    f32x4 acc[2][8] = {};
    #pragma unroll
    for (int ks = 0; ks < 2; ++ks) {
        int kk = ks * 32;
        bf16x8 a[2], bfr[8];
        #pragma unroll
        for (int mf = 0; mf < 2; ++mf)
            a[mf] = *reinterpret_cast<const bf16x8*>(h + (size_t)(r0 + mf * 16 + lrow) * NN + kk + lk);
        #pragma unroll
        for (int nf = 0; nf < 8; ++nf)
            bfr[nf] = *reinterpret_cast<const bf16x8*>(Wpb + (size_t)(c0 + nf * 16 + lrow) * NN + kk + lk);
        #pragma unroll
        for (int mf = 0; mf < 2; ++mf)
            #pragma unroll
            for (int nf = 0; nf < 8; ++nf)
                acc[mf][nf] = __builtin_amdgcn_mfma_f32_16x16x32_bf16(a[mf], bfr[nf], acc[mf][nf], 0, 0, 0);
    }
    int rb = (lane >> 4) * 4;
    #pragma unroll
    for (int nf = 0; nf < 8; ++nf) {
        int col = c0 + nf * 16 + (lane & 15);
        float bias = bp[col];
        #pragma unroll
        for (int mf = 0; mf < 2; ++mf) {
            #pragma unroll
            for (int r = 0; r < 4; ++r) {
                int row = r0 + mf * 16 + rb + r;
                out[(size_t)row * DD + col] = acc[mf][nf][r] + bias;
            }
        }
    }
}

extern "C" void kernel_launch(void* const* d_in, const int* in_sizes, int n_in,
                              void* d_out, int out_size, void* d_ws, size_t ws_size,
                              hipStream_t stream) {
    const float* x    = (const float*)d_in[0];
    const float* ln_w = (const float*)d_in[1];
    const float* ln_b = (const float*)d_in[2];
    const float* Wi   = (const float*)d_in[3];
    const float* bi   = (const float*)d_in[4];
    const float* Wf   = (const float*)d_in[5];
    const float* bfv  = (const float*)d_in[6];
    const float* Wz   = (const float*)d_in[7];
    const float* bz   = (const float*)d_in[8];
    const float* Wo   = (const float*)d_in[9];
    const float* bo   = (const float*)d_in[10];
    const float* Wp   = (const float*)d_in[11];
    const float* bp   = (const float*)d_in[12];
    float* out = (float*)d_out;

    // gates fp32 [32768][256] at d_out floats [0, 8.39M)  (33.5 MB; dead before out_gemm)
    float* gates = (float*)d_out;
    // chunk summaries in dead d_out space (floats from 9M; 5 x 131072 floats)
    float* sbase = (float*)d_out + 9 * 1024 * 1024;
    float* sLf = sbase;
    float* sM  = sbase + 1 * (BB * NCHUNK * 64);
    float* sC  = sbase + 2 * (BB * NCHUNK * 64);
    float* cM  = sbase + 3 * (BB * NCHUNK * 64);
    float* cC  = sbase + 4 * (BB * NCHUNK * 64);

    // Small scratch in ws (~5.4 MB)
    char* w = (char*)d_ws;
    ushort_t* h   = (ushort_t*)w; w += (size_t)ROWS * NN * 2;       // 4,194,304
    ushort_t* Wph = (ushort_t*)w; w += 256 * 1024 * 2;              // 524,288
    ushort_t* Wpl = (ushort_t*)w; w += 256 * 1024 * 2;              // 524,288
    ushort_t* Wpb = (ushort_t*)w; w += 1024 * 64 * 2;               // 131,072
    float* b_all  = (float*)w;    w += 256 * 4;                     // 1,024

    prep_kernel<<<386, 256, 0, stream>>>(Wi, bi, Wf, bfv, Wz, bz, Wo, bo, Wp, Wph, Wpl, Wpb, b_all);
    gate_gemm<<<ROWS / 128, 512, 0, stream>>>(x, ln_w, ln_b, Wph, Wpl, b_all, gates);
    scan_a<<<(BB * NCHUNK) / 4, 256, 0, stream>>>(gates, sLf, sM, sC);
    scan_b<<<BB, 64, 0, stream>>>(sLf, sM, sC, cM, cC);
    scan_c<<<(BB * NCHUNK) / 4, 256, 0, stream>>>(gates, cM, cC, h);
    out_gemm<<<(ROWS / 32) * 2, 256, 0, stream>>>(h, Wpb, bp, out);
}